// Round 10
// baseline (18510.577 us; speedup 1.0000x reference)
//
#include <hip/hip_runtime.h>
#include <math.h>

#define Nn 131072
#define Ee 524288
#define NT 8192          // node tiles (16 rows each)
#define FM 104           // fm row stride (floats)

typedef __attribute__((ext_vector_type(8))) short short8;
typedef __attribute__((ext_vector_type(4))) float f32x4;
typedef unsigned short ushort_t;
typedef unsigned int uint32;

__device__ __forceinline__ f32x4 mfma16(short8 a, short8 b, f32x4 c) {
    return __builtin_amdgcn_mfma_f32_16x16x32_bf16(a, b, c, 0, 0, 0);
}

__device__ __forceinline__ uint32 rne_bf16(float x) {
    uint32 u = __float_as_uint(x);
    return (u + 0x7FFFu + ((u >> 16) & 1u)) >> 16;
}

// fp32 -> 3 bf16 limbs (hi, mid, lo); hi+mid+lo ~= x to ~2^-27 rel.
__device__ __forceinline__ void split3(float x, uint32& h, uint32& m, uint32& l) {
    h = rne_bf16(x);
    float hf = __uint_as_float(h << 16);
    float r1 = x - hf;
    m = rne_bf16(r1);
    float mf = __uint_as_float(m << 16);
    float r2 = r1 - mf;
    l = rne_bf16(r2);
}

__device__ __forceinline__ float recon3(ushort_t a, ushort_t b, ushort_t c) {
    return __uint_as_float((uint32)a << 16) + __uint_as_float((uint32)b << 16) +
           __uint_as_float((uint32)c << 16);
}

// Swizzled act format (MS = msg, HS = h), each:
//   [T:8192][g:0..3][limb:0..2] -> 1 KB chunk; within chunk: ushort slot
//   (q*16 + m)*8 + j, where node n = T*16+m, k-dim kk = g*32 + q*8 + j.
//   kk 0..99 valid, 100..127 zero-pad.
// Chunk base (ushorts): ((size_t)(T*4+g)*3 + limb) * 512.

// ---------------------------------------------------------------- diag / zero
__global__ void diag_kernel(float* out, float val) {
    int n = blockIdx.x * 256 + threadIdx.x;
    if (n < Nn) out[n] = (n == 0) ? val : 0.f;
}
__global__ void zero_ints(int* p, int n) {
    int i = blockIdx.x * 256 + threadIdx.x;
    if (i < n) p[i] = 0;
}
// zero pad region: g=3 chunks, lanes q>=1 fully + q=0 j>=4, both arrays
__global__ void zero_swz(ushort_t* HS, ushort_t* MS) {
    int T = blockIdx.x;                  // 8192
    int tid = threadIdx.x;               // 192 = 3 limbs x 64 lanes
    int l = tid >> 6, lane = tid & 63;
    size_t cb = ((size_t)(T * 4 + 3) * 3 + l) * 512 + (size_t)lane * 8;
    if (lane < 16) {
        *(uint2*)(HS + cb + 4) = make_uint2(0, 0);
        *(uint2*)(MS + cb + 4) = make_uint2(0, 0);
    } else {
        *(uint4*)(HS + cb) = make_uint4(0, 0, 0, 0);
        *(uint4*)(MS + cb) = make_uint4(0, 0, 0, 0);
    }
}

// ---------------------------------------------------------------- CSR build
__global__ void hist_kernel(const int* __restrict__ er, const int* __restrict__ ec,
                            int* __restrict__ cnt_f, int* __restrict__ cnt_b) {
    int e = blockIdx.x * 256 + threadIdx.x;
    atomicAdd(&cnt_f[er[e]], 1);
    atomicAdd(&cnt_b[ec[e]], 1);
}

__global__ __launch_bounds__(1024) void scan_kernel(const int* __restrict__ cnt,
                                                    int* __restrict__ ptr, int n) {
    __shared__ int sums[1024];
    int t = threadIdx.x;
    int chunk = n >> 10;
    int base = t * chunk;
    int s = 0;
    for (int i = 0; i < chunk; i++) s += cnt[base + i];
    sums[t] = s;
    __syncthreads();
    for (int off = 1; off < 1024; off <<= 1) {
        int v = (t >= off) ? sums[t - off] : 0;
        __syncthreads();
        sums[t] += v;
        __syncthreads();
    }
    int run = (t == 0) ? 0 : sums[t - 1];
    for (int i = 0; i < chunk; i++) { ptr[base + i] = run; run += cnt[base + i]; }
    if (t == 1023) ptr[n] = run;
}

__global__ void fill_kernel(const int* __restrict__ er, const int* __restrict__ ec,
                            int* __restrict__ ptr_f, int* __restrict__ ptr_b,
                            int* __restrict__ src_f, int* __restrict__ src_b) {
    int e = blockIdx.x * 256 + threadIdx.x;
    int r = er[e], c = ec[e];
    int p = atomicAdd(&ptr_f[r], 1); src_f[p] = c;
    int q = atomicAdd(&ptr_b[c], 1); src_b[q] = r;
}

// ---------------------------------------------------------------- weight prep
// GRU: Wt[c=4d+g][k], c<400 (25 tiles); k<128: Wih (kk=k), k>=128: Whh (kk=k-128).
__global__ void prep_gru_w(const float* __restrict__ Wih, const float* __restrict__ Whh,
                           const float* __restrict__ bih, const float* __restrict__ bhh,
                           ushort_t* __restrict__ W0, ushort_t* __restrict__ W1,
                           ushort_t* __restrict__ W2, float* __restrict__ bg) {
    int gid = blockIdx.x * 256 + threadIdx.x;
    if (gid >= 400 * 256) return;
    int c = gid >> 8, k = gid & 255;
    int d = c >> 2, g = c & 3;      // d < 100
    float w = 0.f;
    if (k < 100) {
        if (g == 0)      w = Wih[d * 100 + k];
        else if (g == 1) w = Wih[(100 + d) * 100 + k];
        else if (g == 2) w = Wih[(200 + d) * 100 + k];
    } else if (k >= 128 && k < 228) {
        int kk = k - 128;
        if (g == 0)      w = Whh[d * 100 + kk];
        else if (g == 1) w = Whh[(100 + d) * 100 + kk];
        else if (g == 3) w = Whh[(200 + d) * 100 + kk];
    }
    uint32 h, m, l; split3(w, h, m, l);
    W0[gid] = (ushort_t)h; W1[gid] = (ushort_t)m; W2[gid] = (ushort_t)l;
    if (k == 0) {
        float b;
        if (g == 0)      b = bih[d] + bhh[d];
        else if (g == 1) b = bih[100 + d] + bhh[100 + d];
        else if (g == 2) b = bih[200 + d];
        else             b = bhh[200 + d];
        bg[c] = b;
    }
}

// msg MLP: W1t[c<64][k<128] (c=hidden col, k=h dim), W2t[c<112][k<64]
__global__ void prep_msg_w(const float* __restrict__ W1, const float* __restrict__ b1,
                           const float* __restrict__ W2, const float* __restrict__ b2,
                           ushort_t* __restrict__ A0, ushort_t* __restrict__ A1,
                           ushort_t* __restrict__ A2, float* __restrict__ b1p,
                           ushort_t* __restrict__ B0, ushort_t* __restrict__ B1,
                           ushort_t* __restrict__ B2, float* __restrict__ b2p) {
    int gid = blockIdx.x * 256 + threadIdx.x;
    if (gid < 8192) {
        int c = gid >> 7, k = gid & 127;
        float w = (c < 50 && k < 100) ? W1[k * 50 + c] : 0.f;
        uint32 h, m, l; split3(w, h, m, l);
        A0[gid] = (ushort_t)h; A1[gid] = (ushort_t)m; A2[gid] = (ushort_t)l;
        if (k == 0) b1p[c] = (c < 50) ? b1[c] : 0.f;
    } else if (gid < 8192 + 7168) {
        int t = gid - 8192;
        int c = t >> 6, k = t & 63;
        float w = (c < 100 && k < 50) ? W2[k * 100 + c] : 0.f;
        uint32 h, m, l; split3(w, h, m, l);
        B0[t] = (ushort_t)h; B1[t] = (ushort_t)m; B2[t] = (ushort_t)l;
        if (k == 0) b2p[c] = (c < 100) ? b2[c] : 0.f;
    }
}

// ---------------------------------------------------------------- init h
// thread per (frag f, node n): computes 8 h dims, writes swizzled limbs
__global__ void init_h_kernel(const float* __restrict__ feat, const float* __restrict__ W,
                              const float* __restrict__ b, ushort_t* __restrict__ HS) {
    int gid = blockIdx.x * 256 + threadIdx.x;   // 13*N
    int n = gid & (Nn - 1);
    int f = gid >> 17;                           // 0..12
    float4 fe = *(const float4*)&feat[n * 4];
    uint32 H[8], M[8], L[8];
#pragma unroll
    for (int j = 0; j < 8; j++) {
        int d = f * 8 + j;
        float acc = 0.f;
        if (d < 100) {
            acc = b[d] + fe.x * W[d] + fe.y * W[100 + d] +
                  fe.z * W[200 + d] + fe.w * W[300 + d];
        }
        split3(acc, H[j], M[j], L[j]);
    }
    int T = n >> 4, m = n & 15, g = f >> 2, q = f & 3;
    size_t cb = ((size_t)(T * 4 + g) * 3) * 512 + (size_t)(q * 16 + m) * 8;
    *(uint4*)(HS + cb)        = make_uint4(H[0]|(H[1]<<16), H[2]|(H[3]<<16), H[4]|(H[5]<<16), H[6]|(H[7]<<16));
    *(uint4*)(HS + cb + 512)  = make_uint4(M[0]|(M[1]<<16), M[2]|(M[3]<<16), M[4]|(M[5]<<16), M[6]|(M[7]<<16));
    *(uint4*)(HS + cb + 1024) = make_uint4(L[0]|(L[1]<<16), L[2]|(L[3]<<16), L[4]|(L[5]<<16), L[6]|(L[7]<<16));
}

// ---------------------------------------------------------------- msg MLP (MFMA)
// fm = relu(h @ W1 + b1) @ W2 + b2 ; h read coalesced from HS.
__global__ __launch_bounds__(256, 2) void msg_mfma(
    const ushort_t* __restrict__ HS,
    const ushort_t* __restrict__ A0, const ushort_t* __restrict__ A1,
    const ushort_t* __restrict__ A2, const float* __restrict__ b1p,
    const ushort_t* __restrict__ B0, const ushort_t* __restrict__ B1,
    const ushort_t* __restrict__ B2, const float* __restrict__ b2p,
    float* __restrict__ fm) {
    __shared__ ushort_t C1[3][64][72];
    const int tid = threadIdx.x;
    const int u = tid >> 6;          // wave = node tile
    const int lane = tid & 63;
    const int m = lane & 15, q = lane >> 4;
    const int n0 = blockIdx.x * 64;
    const int n = n0 + u * 16 + m;
    const int Tw = blockIdx.x * 4 + u;

    f32x4 z = {0.f, 0.f, 0.f, 0.f};
    f32x4 a1[4] = {z, z, z, z};

    for (int kc = 0; kc < 4; kc++) {
        size_t cb = ((size_t)(Tw * 4 + kc) * 3) * 512 + (size_t)lane * 8;
        short8 f0 = *(const short8*)(HS + cb);
        short8 f1 = *(const short8*)(HS + cb + 512);
        short8 f2 = *(const short8*)(HS + cb + 1024);
#pragma unroll
        for (int t = 0; t < 4; t++) {
            int off = (t * 16 + m) * 128 + kc * 32 + q * 8;
            short8 w0 = *(const short8*)(A0 + off);
            short8 w1 = *(const short8*)(A1 + off);
            short8 w2 = *(const short8*)(A2 + off);
            a1[t] = mfma16(w0, f0, a1[t]);
            a1[t] = mfma16(w0, f1, a1[t]);
            a1[t] = mfma16(w1, f0, a1[t]);
            a1[t] = mfma16(w0, f2, a1[t]);
            a1[t] = mfma16(w2, f0, a1[t]);
            a1[t] = mfma16(w1, f1, a1[t]);
        }
    }
    // epilogue 1: relu + split -> LDS
#pragma unroll
    for (int t = 0; t < 4; t++) {
        int c0 = t * 16 + 4 * q;
        float4 bb = *(const float4*)&b1p[c0];
        float v0 = fmaxf(a1[t][0] + bb.x, 0.f);
        float v1 = fmaxf(a1[t][1] + bb.y, 0.f);
        float v2 = fmaxf(a1[t][2] + bb.z, 0.f);
        float v3 = fmaxf(a1[t][3] + bb.w, 0.f);
        uint32 h0, m0, l0, h1, m1, l1, h2, m2, l2, h3, m3, l3;
        split3(v0, h0, m0, l0); split3(v1, h1, m1, l1);
        split3(v2, h2, m2, l2); split3(v3, h3, m3, l3);
        int nl = u * 16 + m;
        *(uint2*)&C1[0][nl][c0] = make_uint2(h0 | (h1 << 16), h2 | (h3 << 16));
        *(uint2*)&C1[1][nl][c0] = make_uint2(m0 | (m1 << 16), m2 | (m3 << 16));
        *(uint2*)&C1[2][nl][c0] = make_uint2(l0 | (l1 << 16), l2 | (l3 << 16));
    }
    __syncthreads();

    f32x4 a2[7] = {z, z, z, z, z, z, z};
    for (int kc = 0; kc < 2; kc++) {
        int nl = u * 16 + m;
        short8 c0f = *(const short8*)&C1[0][nl][kc * 32 + q * 8];
        short8 c1f = *(const short8*)&C1[1][nl][kc * 32 + q * 8];
        short8 c2f = *(const short8*)&C1[2][nl][kc * 32 + q * 8];
#pragma unroll
        for (int t = 0; t < 7; t++) {
            int off = (t * 16 + m) * 64 + kc * 32 + q * 8;
            short8 w0 = *(const short8*)(B0 + off);
            short8 w1 = *(const short8*)(B1 + off);
            short8 w2 = *(const short8*)(B2 + off);
            a2[t] = mfma16(w0, c0f, a2[t]);
            a2[t] = mfma16(w0, c1f, a2[t]);
            a2[t] = mfma16(w1, c0f, a2[t]);
            a2[t] = mfma16(w0, c2f, a2[t]);
            a2[t] = mfma16(w2, c0f, a2[t]);
            a2[t] = mfma16(w1, c1f, a2[t]);
        }
    }
#pragma unroll
    for (int t = 0; t < 7; t++) {
        int c0 = t * 16 + 4 * q;
        if (c0 < FM) {       // 100..103 write zeros naturally (padded weights/bias)
            float4 bb = *(const float4*)&b2p[c0];
            float4 o;
            o.x = a2[t][0] + bb.x; o.y = a2[t][1] + bb.y;
            o.z = a2[t][2] + bb.z; o.w = a2[t][3] + bb.w;
            *(float4*)&fm[(size_t)n * FM + c0] = o;
        }
    }
}

// ---------------------------------------------------------------- gather (CSR)
// thread per (frag f, node n): sum 8 k-dims over in-edges, split, write MS frag
__global__ void gather8(const float* __restrict__ fm, const int* __restrict__ ptr,
                        const int* __restrict__ idx, ushort_t* __restrict__ MS) {
    int gid = blockIdx.x * 256 + threadIdx.x;   // 13*N
    int n = gid & (Nn - 1);
    int f = gid >> 17;                           // 0..12
    int s = (n == 0) ? 0 : ptr[n - 1];
    int e = ptr[n];
    int kb = f * 8;
    float acc[8] = {0.f, 0.f, 0.f, 0.f, 0.f, 0.f, 0.f, 0.f};
    for (int i = s; i < e; i++) {
        const float* src = fm + (size_t)idx[i] * FM + kb;
        float4 a = *(const float4*)src;
        float4 b = *(const float4*)(src + 4);
        acc[0] += a.x; acc[1] += a.y; acc[2] += a.z; acc[3] += a.w;
        acc[4] += b.x; acc[5] += b.y; acc[6] += b.z; acc[7] += b.w;
    }
    uint32 H[8], M[8], L[8];
#pragma unroll
    for (int j = 0; j < 8; j++) split3(acc[j], H[j], M[j], L[j]);
    int T = n >> 4, m = n & 15, g = f >> 2, q = f & 3;
    size_t cb = ((size_t)(T * 4 + g) * 3) * 512 + (size_t)(q * 16 + m) * 8;
    *(uint4*)(MS + cb)        = make_uint4(H[0]|(H[1]<<16), H[2]|(H[3]<<16), H[4]|(H[5]<<16), H[6]|(H[7]<<16));
    *(uint4*)(MS + cb + 512)  = make_uint4(M[0]|(M[1]<<16), M[2]|(M[3]<<16), M[4]|(M[5]<<16), M[6]|(M[7]<<16));
    *(uint4*)(MS + cb + 1024) = make_uint4(L[0]|(L[1]<<16), L[2]|(L[3]<<16), L[4]|(L[5]<<16), L[6]|(L[7]<<16));
}

// ---------------------------------------------------------------- GRU (MFMA) v8
// 64-row blocks (2048), 25 col-tiles; wave0: 7 tiles, waves1-3: 6 (ct=4t+wave).
// No LDS, no mid-loop barriers. Act loads are fully-coalesced 16B/lane chunk
// reads from MS (kc<4) / HS (kc>=4) — zero split VALU in the k-loop.
// Product-major passes: MFMA dep distance 28. One barrier before h update.
__global__ __launch_bounds__(256, 2) void gru_mfma(
    ushort_t* __restrict__ HS, const ushort_t* __restrict__ MS,
    const ushort_t* __restrict__ W0, const ushort_t* __restrict__ W1,
    const ushort_t* __restrict__ W2, const float* __restrict__ bg) {
    const int tid = threadIdx.x;
    const int wave = tid >> 6;
    const int lane = tid & 63;
    const int m = lane & 15, q = lane >> 4;
    const int Tb0 = blockIdx.x * 4;
    const int n0 = blockIdx.x * 64;

    f32x4 z = {0.f, 0.f, 0.f, 0.f};
    f32x4 acc[7][4];
#pragma unroll
    for (int t = 0; t < 7; t++)
#pragma unroll
        for (int rf = 0; rf < 4; rf++) acc[t][rf] = z;

    int woff[7];
#pragma unroll
    for (int t = 0; t < 7; t++) {
        int ct = t * 4 + wave;
        woff[t] = (ct < 25) ? ((ct * 16 + m) * 256 + q * 8) : 0;
    }

#define GPASS(Wreg, Fr)                                          \
    _Pragma("unroll")                                            \
    for (int t = 0; t < 7; t++) if (t < 6 || wave == 0) {        \
        _Pragma("unroll")                                        \
        for (int rf = 0; rf < 4; rf++)                           \
            acc[t][rf] = mfma16(Wreg[t], Fr[rf], acc[t][rf]);    \
    }

    for (int kc = 0; kc < 8; kc++) {
        const ushort_t* arr = (kc < 4) ? MS : HS;
        const int g = kc & 3;
        const int ko = kc * 32;
        short8 f0[4], f1[4], f2[4];
#pragma unroll
        for (int rf = 0; rf < 4; rf++) {
            size_t cb = ((size_t)((Tb0 + rf) * 4 + g) * 3) * 512 + (size_t)lane * 8;
            f0[rf] = *(const short8*)(arr + cb);
            f1[rf] = *(const short8*)(arr + cb + 512);
            f2[rf] = *(const short8*)(arr + cb + 1024);
        }
        short8 w[7];
#pragma unroll
        for (int t = 0; t < 7; t++) if (t < 6 || wave == 0)
            w[t] = *(const short8*)(W0 + woff[t] + ko);
        GPASS(w, f0);                       // w0*f0
        GPASS(w, f1);                       // w0*f1
        GPASS(w, f2);                       // w0*f2
#pragma unroll
        for (int t = 0; t < 7; t++) if (t < 6 || wave == 0)
            w[t] = *(const short8*)(W1 + woff[t] + ko);
        GPASS(w, f0);                       // w1*f0
        GPASS(w, f1);                       // w1*f1
#pragma unroll
        for (int t = 0; t < 7; t++) if (t < 6 || wave == 0)
            w[t] = *(const short8*)(W2 + woff[t] + ko);
        GPASS(w, f0);                       // w2*f0
    }
#undef GPASS

    __syncthreads();    // all HS reads complete before in-place h overwrite

    // epilogue: gates, h update, write swizzled limbs
#pragma unroll
    for (int t = 0; t < 7; t++) if (t < 6 || wave == 0) {
        const int ct = t * 4 + wave;        // < 25
        const int d = ct * 4 + q;           // < 100
        float4 b4 = *(const float4*)&bg[ct * 16 + 4 * q];
        const int fh = d >> 3, gh = fh >> 2, qh = fh & 3, j = d & 7;
#pragma unroll
        for (int rf = 0; rf < 4; rf++) {
            int T = Tb0 + rf;
            size_t cb = ((size_t)(T * 4 + gh) * 3) * 512 + (size_t)(qh * 16 + m) * 8 + j;
            float hold = recon3(HS[cb], HS[cb + 512], HS[cb + 1024]);
            float rp = acc[t][rf][0] + b4.x;
            float zp = acc[t][rf][1] + b4.y;
            float np = acc[t][rf][2] + b4.z;
            float hh = acc[t][rf][3] + b4.w;
            float rr = 1.f / (1.f + __expf(-rp));
            float zz = 1.f / (1.f + __expf(-zp));
            float nw = tanhf(np + rr * hh);
            float hnew = (1.f - zz) * nw + zz * hold;
            uint32 h, mm, l; split3(hnew, h, mm, l);
            HS[cb] = (ushort_t)h; HS[cb + 512] = (ushort_t)mm;
            HS[cb + 1024] = (ushort_t)l;
        }
    }
}

// ---------------------------------------------------------------- classifier
__global__ __launch_bounds__(256) void classifier(
    const ushort_t* __restrict__ HS, const float* __restrict__ W1,
    const float* __restrict__ b1, const float* __restrict__ W2,
    const float* __restrict__ b2, float* __restrict__ out) {
    __shared__ float Wc[3000];
    __shared__ float bc[30];
    __shared__ float w2[30];
    int tid = threadIdx.x;
    for (int i = tid; i < 3000; i += 256) Wc[i] = W1[i];
    if (tid < 30) { bc[tid] = b1[tid]; w2[tid] = W2[tid]; }
    __syncthreads();
    int n = blockIdx.x * 256 + tid;
    int T = n >> 4, m = n & 15;
    float a[30];
#pragma unroll
    for (int j = 0; j < 30; j++) a[j] = bc[j];
    for (int f = 0; f < 13; f++) {
        int g = f >> 2, q = f & 3;
        size_t cb = ((size_t)(T * 4 + g) * 3) * 512 + (size_t)(q * 16 + m) * 8;
        int jmax = (f == 12) ? 4 : 8;
        for (int j = 0; j < jmax; j++) {
            float hv = recon3(HS[cb + j], HS[cb + 512 + j], HS[cb + 1024 + j]);
            int k = f * 8 + j;
#pragma unroll
            for (int jj = 0; jj < 30; jj++) a[jj] = fmaf(hv, Wc[k * 30 + jj], a[jj]);
        }
    }
    float s = b2[0];
#pragma unroll
    for (int j = 0; j < 30; j++) s = fmaf(fmaxf(a[j], 0.f), w2[j], s);
    out[n] = s;
}

// ---------------------------------------------------------------- launch
extern "C" void kernel_launch(void* const* d_in, const int* in_sizes, int n_in,
                              void* d_out, int out_size, void* d_ws, size_t ws_size,
                              hipStream_t stream) {
    const float* feat     = (const float*)d_in[0];
    const int*   er       = (const int*)d_in[1];
    const int*   ec       = (const int*)d_in[2];
    const float* init_W   = (const float*)d_in[3];
    const float* init_b   = (const float*)d_in[4];
    const float* fmsg_W1  = (const float*)d_in[5];
    const float* fmsg_b1  = (const float*)d_in[6];
    const float* fmsg_W2  = (const float*)d_in[7];
    const float* fmsg_b2  = (const float*)d_in[8];
    const float* bmsg_W1  = (const float*)d_in[9];
    const float* bmsg_b1  = (const float*)d_in[10];
    const float* bmsg_W2  = (const float*)d_in[11];
    const float* bmsg_b2  = (const float*)d_in[12];
    const float* fgru_Wih = (const float*)d_in[13];
    const float* fgru_Whh = (const float*)d_in[14];
    const float* fgru_bih = (const float*)d_in[15];
    const float* fgru_bhh = (const float*)d_in[16];
    const float* bgru_Wih = (const float*)d_in[17];
    const float* bgru_Whh = (const float*)d_in[18];
    const float* bgru_bih = (const float*)d_in[19];
    const float* bgru_bhh = (const float*)d_in[20];
    const float* cls_W1   = (const float*)d_in[21];
    const float* cls_b1   = (const float*)d_in[22];
    const float* cls_W2   = (const float*)d_in[23];
    const float* cls_b2   = (const float*)d_in[24];
    float* out = (float*)d_out;

    char* base = (char*)d_ws;
    size_t off = 0;
    auto alloc = [&](size_t bytes) -> void* {
        void* p = base + off;
        off += (bytes + 15) & ~(size_t)15;
        return p;
    };

    const size_t swzBytes = (size_t)NT * 4 * 3 * 1024;   // 100.66 MB
    ushort_t* HS = (ushort_t*)alloc(swzBytes);
    ushort_t* MS = (ushort_t*)alloc(swzBytes);
    float*    fm = (float*)alloc((size_t)Nn * FM * 4);   // 54.5 MB

    ushort_t* fWg0 = (ushort_t*)alloc(400 * 256 * 2);
    ushort_t* fWg1 = (ushort_t*)alloc(400 * 256 * 2);
    ushort_t* fWg2 = (ushort_t*)alloc(400 * 256 * 2);
    ushort_t* bWg0 = (ushort_t*)alloc(400 * 256 * 2);
    ushort_t* bWg1 = (ushort_t*)alloc(400 * 256 * 2);
    ushort_t* bWg2 = (ushort_t*)alloc(400 * 256 * 2);
    ushort_t* fA0  = (ushort_t*)alloc(8192 * 2);
    ushort_t* fA1  = (ushort_t*)alloc(8192 * 2);
    ushort_t* fA2  = (ushort_t*)alloc(8192 * 2);
    ushort_t* bA0  = (ushort_t*)alloc(8192 * 2);
    ushort_t* bA1  = (ushort_t*)alloc(8192 * 2);
    ushort_t* bA2  = (ushort_t*)alloc(8192 * 2);
    ushort_t* fB0  = (ushort_t*)alloc(7168 * 2);
    ushort_t* fB1  = (ushort_t*)alloc(7168 * 2);
    ushort_t* fB2  = (ushort_t*)alloc(7168 * 2);
    ushort_t* bB0  = (ushort_t*)alloc(7168 * 2);
    ushort_t* bB1  = (ushort_t*)alloc(7168 * 2);
    ushort_t* bB2  = (ushort_t*)alloc(7168 * 2);

    float* bgf  = (float*)alloc(400 * 4);
    float* bgb  = (float*)alloc(400 * 4);
    float* b1pf = (float*)alloc(64 * 4);
    float* b1pb = (float*)alloc(64 * 4);
    float* b2pf = (float*)alloc(112 * 4);
    float* b2pb = (float*)alloc(112 * 4);

    int* ptr_f = (int*)alloc((Nn + 1) * 4);
    int* ptr_b = (int*)alloc((Nn + 1) * 4);
    int* cnt   = (int*)alloc(2 * (size_t)Nn * 4);
    int* cnt_f = cnt;
    int* cnt_b = cnt + Nn;
    int* src_f = (int*)alloc((size_t)Ee * 4);
    int* src_b = (int*)alloc((size_t)Ee * 4);

    if (ws_size < off) {
        // diagnostic: absmax will report ~ws_size
        diag_kernel<<<(Nn + 255) / 256, 256, 0, stream>>>(out, (float)ws_size);
        return;
    }

    // CSR build
    zero_ints<<<(2 * Nn + 255) / 256, 256, 0, stream>>>(cnt, 2 * Nn);
    hist_kernel<<<Ee / 256, 256, 0, stream>>>(er, ec, cnt_f, cnt_b);
    scan_kernel<<<1, 1024, 0, stream>>>(cnt_f, ptr_f, Nn);
    scan_kernel<<<1, 1024, 0, stream>>>(cnt_b, ptr_b, Nn);
    fill_kernel<<<Ee / 256, 256, 0, stream>>>(er, ec, ptr_f, ptr_b, src_f, src_b);

    // weight prep (split to 3 bf16 limbs)
    prep_gru_w<<<(400 * 256 + 255) / 256, 256, 0, stream>>>(
        fgru_Wih, fgru_Whh, fgru_bih, fgru_bhh, fWg0, fWg1, fWg2, bgf);
    prep_gru_w<<<(400 * 256 + 255) / 256, 256, 0, stream>>>(
        bgru_Wih, bgru_Whh, bgru_bih, bgru_bhh, bWg0, bWg1, bWg2, bgb);
    prep_msg_w<<<(15360 + 255) / 256, 256, 0, stream>>>(
        fmsg_W1, fmsg_b1, fmsg_W2, fmsg_b2, fA0, fA1, fA2, b1pf, fB0, fB1, fB2, b2pf);
    prep_msg_w<<<(15360 + 255) / 256, 256, 0, stream>>>(
        bmsg_W1, bmsg_b1, bmsg_W2, bmsg_b2, bA0, bA1, bA2, b1pb, bB0, bB1, bB2, b2pb);

    // swizzled act pads + h init
    zero_swz<<<NT, 192, 0, stream>>>(HS, MS);
    init_h_kernel<<<13 * Nn / 256, 256, 0, stream>>>(feat, init_W, init_b, HS);

    const int gTile = Nn / 64;            // 2048 (msg, gru)
    const int gGath = 13 * Nn / 256;      // 6656

    for (int rd = 0; rd < 20; rd++) {
        msg_mfma<<<gTile, 256, 0, stream>>>(HS, fA0, fA1, fA2, b1pf,
                                            fB0, fB1, fB2, b2pf, fm);
        gather8<<<gGath, 256, 0, stream>>>(fm, ptr_f, src_f, MS);
        gru_mfma<<<gTile, 256, 0, stream>>>(HS, MS, fWg0, fWg1, fWg2, bgf);

        msg_mfma<<<gTile, 256, 0, stream>>>(HS, bA0, bA1, bA2, b1pb,
                                            bB0, bB1, bB2, b2pb, fm);
        gather8<<<gGath, 256, 0, stream>>>(fm, ptr_b, src_b, MS);
        gru_mfma<<<gTile, 256, 0, stream>>>(HS, MS, bWg0, bWg1, bWg2, bgb);
    }

    classifier<<<Nn / 256, 256, 0, stream>>>(HS, cls_W1, cls_b1,
                                             cls_W2, cls_b2, out);
}

// Round 11
// 15338.760 us; speedup vs baseline: 1.2068x; 1.2068x over previous
//
#include <hip/hip_runtime.h>
#include <math.h>

#define Nn 131072
#define Ee 524288
#define NT 8192          // node tiles (16 rows each)
#define FM 104           // fm row stride (floats)

typedef __attribute__((ext_vector_type(8))) short short8;
typedef __attribute__((ext_vector_type(4))) float f32x4;
typedef unsigned short ushort_t;
typedef unsigned int uint32;

__device__ __forceinline__ f32x4 mfma16(short8 a, short8 b, f32x4 c) {
    return __builtin_amdgcn_mfma_f32_16x16x32_bf16(a, b, c, 0, 0, 0);
}

__device__ __forceinline__ uint32 rne_bf16(float x) {
    uint32 u = __float_as_uint(x);
    return (u + 0x7FFFu + ((u >> 16) & 1u)) >> 16;
}

// fp32 -> 3 bf16 limbs (hi, mid, lo); hi+mid+lo ~= x to ~2^-27 rel.
__device__ __forceinline__ void split3(float x, uint32& h, uint32& m, uint32& l) {
    h = rne_bf16(x);
    float hf = __uint_as_float(h << 16);
    float r1 = x - hf;
    m = rne_bf16(r1);
    float mf = __uint_as_float(m << 16);
    float r2 = r1 - mf;
    l = rne_bf16(r2);
}

__device__ __forceinline__ float recon3(ushort_t a, ushort_t b, ushort_t c) {
    return __uint_as_float((uint32)a << 16) + __uint_as_float((uint32)b << 16) +
           __uint_as_float((uint32)c << 16);
}

// Unified swizzled act array AS: per node-tile T, 7 k-groups g, 3 limbs ->
// 1 KB chunk; chunk base (ushorts) = ((T*7+g)*3+limb)*512; slot (q*16+m)*8+j
// for node n=T*16+m, kk = g*32+q*8+j in [0,224):
//   kk 0..99   msg (frag f=kk>>3 in 0..12)
//   kk 100..111 zero (f12 j>=4, f13)
//   kk 112..211 h   (f 14..26)
//   kk 212..223 zero (f26 j>=4, f27)
// GRU weights WS swizzled identically per col-tile ct:
//   chunk = ((ct*7+kc)*3+limb)*512, slot (q*16+mrow)*8+j, k = kc*32+q*8+j.

// ---------------------------------------------------------------- diag / zero
__global__ void diag_kernel(float* out, float val) {
    int n = blockIdx.x * 256 + threadIdx.x;
    if (n < Nn) out[n] = (n == 0) ? val : 0.f;
}
__global__ void zero_ints(int* p, int n) {
    int i = blockIdx.x * 256 + threadIdx.x;
    if (i < n) p[i] = 0;
}
// zero pad fragments of AS (ws is poisoned every launch)
__global__ void zero_swz(ushort_t* AS) {
    int T = blockIdx.x;                  // NT
    int tid = threadIdx.x;               // 64; use 48: l=tid/16, mm=tid%16
    if (tid >= 48) return;
    int l = tid >> 4, mm = tid & 15;
    size_t c3 = ((size_t)(T * 7 + 3) * 3 + l) * 512;
    size_t c6 = ((size_t)(T * 7 + 6) * 3 + l) * 512;
    *(uint2*)(AS + c3 + mm * 8 + 4)        = make_uint2(0, 0);           // f12 j>=4
    *(uint4*)(AS + c3 + (16 + mm) * 8)     = make_uint4(0, 0, 0, 0);     // f13
    *(uint2*)(AS + c6 + (32 + mm) * 8 + 4) = make_uint2(0, 0);           // f26 j>=4
    *(uint4*)(AS + c6 + (48 + mm) * 8)     = make_uint4(0, 0, 0, 0);     // f27
}

// ---------------------------------------------------------------- CSR build
__global__ void hist_kernel(const int* __restrict__ er, const int* __restrict__ ec,
                            int* __restrict__ cnt_f, int* __restrict__ cnt_b) {
    int e = blockIdx.x * 256 + threadIdx.x;
    atomicAdd(&cnt_f[er[e]], 1);
    atomicAdd(&cnt_b[ec[e]], 1);
}

__global__ __launch_bounds__(1024) void scan_kernel(const int* __restrict__ cnt,
                                                    int* __restrict__ ptr, int n) {
    __shared__ int sums[1024];
    int t = threadIdx.x;
    int chunk = n >> 10;
    int base = t * chunk;
    int s = 0;
    for (int i = 0; i < chunk; i++) s += cnt[base + i];
    sums[t] = s;
    __syncthreads();
    for (int off = 1; off < 1024; off <<= 1) {
        int v = (t >= off) ? sums[t - off] : 0;
        __syncthreads();
        sums[t] += v;
        __syncthreads();
    }
    int run = (t == 0) ? 0 : sums[t - 1];
    for (int i = 0; i < chunk; i++) { ptr[base + i] = run; run += cnt[base + i]; }
    if (t == 1023) ptr[n] = run;
}

__global__ void fill_kernel(const int* __restrict__ er, const int* __restrict__ ec,
                            int* __restrict__ ptr_f, int* __restrict__ ptr_b,
                            int* __restrict__ src_f, int* __restrict__ src_b) {
    int e = blockIdx.x * 256 + threadIdx.x;
    int r = er[e], c = ec[e];
    int p = atomicAdd(&ptr_f[r], 1); src_f[p] = c;
    int q = atomicAdd(&ptr_b[c], 1); src_b[q] = r;
}

// ---------------------------------------------------------------- weight prep
// GRU weights -> swizzled WS. col c=4d+g' < 400, k < 224.
__global__ void prep_gru_w(const float* __restrict__ Wih, const float* __restrict__ Whh,
                           const float* __restrict__ bih, const float* __restrict__ bhh,
                           ushort_t* __restrict__ WS, float* __restrict__ bg) {
    int gid = blockIdx.x * 256 + threadIdx.x;
    if (gid >= 400 * 224) return;
    int c = gid / 224, k = gid - c * 224;
    int d = c >> 2, g = c & 3;      // d < 100
    float w = 0.f;
    if (k < 100) {
        if (g == 0)      w = Wih[d * 100 + k];
        else if (g == 1) w = Wih[(100 + d) * 100 + k];
        else if (g == 2) w = Wih[(200 + d) * 100 + k];
    } else if (k >= 112 && k < 212) {
        int kk = k - 112;
        if (g == 0)      w = Whh[d * 100 + kk];
        else if (g == 1) w = Whh[(100 + d) * 100 + kk];
        else if (g == 3) w = Whh[(200 + d) * 100 + kk];
    }
    uint32 h, m, l; split3(w, h, m, l);
    int ct = c >> 4, mr = c & 15, kc = k >> 5, kq = (k >> 3) & 3, j = k & 7;
    size_t base = ((size_t)(ct * 7 + kc) * 3) * 512 + (size_t)(kq * 16 + mr) * 8 + j;
    WS[base] = (ushort_t)h; WS[base + 512] = (ushort_t)m; WS[base + 1024] = (ushort_t)l;
    if (k == 0) {
        float b;
        if (g == 0)      b = bih[d] + bhh[d];
        else if (g == 1) b = bih[100 + d] + bhh[100 + d];
        else if (g == 2) b = bih[200 + d];
        else             b = bhh[200 + d];
        bg[c] = b;
    }
}

// msg MLP: W1t[c<64][k<128] (c=hidden col, k=h dim), W2t[c<112][k<64]
__global__ void prep_msg_w(const float* __restrict__ W1, const float* __restrict__ b1,
                           const float* __restrict__ W2, const float* __restrict__ b2,
                           ushort_t* __restrict__ A0, ushort_t* __restrict__ A1,
                           ushort_t* __restrict__ A2, float* __restrict__ b1p,
                           ushort_t* __restrict__ B0, ushort_t* __restrict__ B1,
                           ushort_t* __restrict__ B2, float* __restrict__ b2p) {
    int gid = blockIdx.x * 256 + threadIdx.x;
    if (gid < 8192) {
        int c = gid >> 7, k = gid & 127;
        float w = (c < 50 && k < 100) ? W1[k * 50 + c] : 0.f;
        uint32 h, m, l; split3(w, h, m, l);
        A0[gid] = (ushort_t)h; A1[gid] = (ushort_t)m; A2[gid] = (ushort_t)l;
        if (k == 0) b1p[c] = (c < 50) ? b1[c] : 0.f;
    } else if (gid < 8192 + 7168) {
        int t = gid - 8192;
        int c = t >> 6, k = t & 63;
        float w = (c < 100 && k < 50) ? W2[k * 100 + c] : 0.f;
        uint32 h, m, l; split3(w, h, m, l);
        B0[t] = (ushort_t)h; B1[t] = (ushort_t)m; B2[t] = (ushort_t)l;
        if (k == 0) b2p[c] = (c < 100) ? b2[c] : 0.f;
    }
}

// ---------------------------------------------------------------- init h
__global__ void init_h_kernel(const float* __restrict__ feat, const float* __restrict__ W,
                              const float* __restrict__ b, ushort_t* __restrict__ AS) {
    int gid = blockIdx.x * 256 + threadIdx.x;   // 13*N
    int n = gid & (Nn - 1);
    int f2 = gid >> 17;                          // 0..12
    float4 fe = *(const float4*)&feat[n * 4];
    uint32 H[8], M[8], L[8];
#pragma unroll
    for (int j = 0; j < 8; j++) {
        int d = f2 * 8 + j;
        float acc = 0.f;
        if (d < 100) {
            acc = b[d] + fe.x * W[d] + fe.y * W[100 + d] +
                  fe.z * W[200 + d] + fe.w * W[300 + d];
        }
        split3(acc, H[j], M[j], L[j]);
    }
    int T = n >> 4, m = n & 15;
    int f = 14 + f2, g = f >> 2, qq = f & 3;
    size_t cb = ((size_t)(T * 7 + g) * 3) * 512 + (size_t)(qq * 16 + m) * 8;
    *(uint4*)(AS + cb)        = make_uint4(H[0]|(H[1]<<16), H[2]|(H[3]<<16), H[4]|(H[5]<<16), H[6]|(H[7]<<16));
    *(uint4*)(AS + cb + 512)  = make_uint4(M[0]|(M[1]<<16), M[2]|(M[3]<<16), M[4]|(M[5]<<16), M[6]|(M[7]<<16));
    *(uint4*)(AS + cb + 1024) = make_uint4(L[0]|(L[1]<<16), L[2]|(L[3]<<16), L[4]|(L[5]<<16), L[6]|(L[7]<<16));
}

// ---------------------------------------------------------------- msg MLP (MFMA)
__global__ __launch_bounds__(256, 2) void msg_mfma(
    const ushort_t* __restrict__ AS,
    const ushort_t* __restrict__ A0, const ushort_t* __restrict__ A1,
    const ushort_t* __restrict__ A2, const float* __restrict__ b1p,
    const ushort_t* __restrict__ B0, const ushort_t* __restrict__ B1,
    const ushort_t* __restrict__ B2, const float* __restrict__ b2p,
    float* __restrict__ fm) {
    __shared__ ushort_t C1[3][64][72];
    const int tid = threadIdx.x;
    const int u = tid >> 6;          // wave = node tile
    const int lane = tid & 63;
    const int m = lane & 15, q = lane >> 4;
    const int n0 = blockIdx.x * 64;
    const int n = n0 + u * 16 + m;
    const int Tw = blockIdx.x * 4 + u;

    f32x4 z = {0.f, 0.f, 0.f, 0.f};
    f32x4 a1[4] = {z, z, z, z};

    for (int kc = 0; kc < 4; kc++) {
        int f = 14 + kc * 4 + q;
        if (f > 27) f = 27;                      // zeros (weights there are 0 too)
        int g = f >> 2, qq = f & 3;
        size_t cb = ((size_t)(Tw * 7 + g) * 3) * 512 + (size_t)(qq * 16 + m) * 8;
        short8 f0 = *(const short8*)(AS + cb);
        short8 f1 = *(const short8*)(AS + cb + 512);
        short8 f2 = *(const short8*)(AS + cb + 1024);
#pragma unroll
        for (int t = 0; t < 4; t++) {
            int off = (t * 16 + m) * 128 + kc * 32 + q * 8;
            short8 w0 = *(const short8*)(A0 + off);
            short8 w1 = *(const short8*)(A1 + off);
            short8 w2 = *(const short8*)(A2 + off);
            a1[t] = mfma16(w0, f0, a1[t]);
            a1[t] = mfma16(w0, f1, a1[t]);
            a1[t] = mfma16(w1, f0, a1[t]);
            a1[t] = mfma16(w0, f2, a1[t]);
            a1[t] = mfma16(w2, f0, a1[t]);
            a1[t] = mfma16(w1, f1, a1[t]);
        }
    }
    // epilogue 1: relu + split -> LDS
#pragma unroll
    for (int t = 0; t < 4; t++) {
        int c0 = t * 16 + 4 * q;
        float4 bb = *(const float4*)&b1p[c0];
        float v0 = fmaxf(a1[t][0] + bb.x, 0.f);
        float v1 = fmaxf(a1[t][1] + bb.y, 0.f);
        float v2 = fmaxf(a1[t][2] + bb.z, 0.f);
        float v3 = fmaxf(a1[t][3] + bb.w, 0.f);
        uint32 h0, m0, l0, h1, m1, l1, h2, m2, l2, h3, m3, l3;
        split3(v0, h0, m0, l0); split3(v1, h1, m1, l1);
        split3(v2, h2, m2, l2); split3(v3, h3, m3, l3);
        int nl = u * 16 + m;
        *(uint2*)&C1[0][nl][c0] = make_uint2(h0 | (h1 << 16), h2 | (h3 << 16));
        *(uint2*)&C1[1][nl][c0] = make_uint2(m0 | (m1 << 16), m2 | (m3 << 16));
        *(uint2*)&C1[2][nl][c0] = make_uint2(l0 | (l1 << 16), l2 | (l3 << 16));
    }
    __syncthreads();

    f32x4 a2[7] = {z, z, z, z, z, z, z};
    for (int kc = 0; kc < 2; kc++) {
        int nl = u * 16 + m;
        short8 c0f = *(const short8*)&C1[0][nl][kc * 32 + q * 8];
        short8 c1f = *(const short8*)&C1[1][nl][kc * 32 + q * 8];
        short8 c2f = *(const short8*)&C1[2][nl][kc * 32 + q * 8];
#pragma unroll
        for (int t = 0; t < 7; t++) {
            int off = (t * 16 + m) * 64 + kc * 32 + q * 8;
            short8 w0 = *(const short8*)(B0 + off);
            short8 w1 = *(const short8*)(B1 + off);
            short8 w2 = *(const short8*)(B2 + off);
            a2[t] = mfma16(w0, c0f, a2[t]);
            a2[t] = mfma16(w0, c1f, a2[t]);
            a2[t] = mfma16(w1, c0f, a2[t]);
            a2[t] = mfma16(w0, c2f, a2[t]);
            a2[t] = mfma16(w2, c0f, a2[t]);
            a2[t] = mfma16(w1, c1f, a2[t]);
        }
    }
#pragma unroll
    for (int t = 0; t < 7; t++) {
        int c0 = t * 16 + 4 * q;
        if (c0 < FM) {
            float4 bb = *(const float4*)&b2p[c0];
            float4 o;
            o.x = a2[t][0] + bb.x; o.y = a2[t][1] + bb.y;
            o.z = a2[t][2] + bb.z; o.w = a2[t][3] + bb.w;
            *(float4*)&fm[(size_t)n * FM + c0] = o;
        }
    }
}

// ---------------------------------------------------------------- gather (CSR)
__global__ void gather8(const float* __restrict__ fm, const int* __restrict__ ptr,
                        const int* __restrict__ idx, ushort_t* __restrict__ AS) {
    int gid = blockIdx.x * 256 + threadIdx.x;   // 13*N
    int n = gid & (Nn - 1);
    int f = gid >> 17;                           // 0..12
    int s = (n == 0) ? 0 : ptr[n - 1];
    int e = ptr[n];
    int kb = f * 8;
    float acc[8] = {0.f, 0.f, 0.f, 0.f, 0.f, 0.f, 0.f, 0.f};
    for (int i = s; i < e; i++) {
        const float* src = fm + (size_t)idx[i] * FM + kb;
        float4 a = *(const float4*)src;
        float4 b = *(const float4*)(src + 4);
        acc[0] += a.x; acc[1] += a.y; acc[2] += a.z; acc[3] += a.w;
        acc[4] += b.x; acc[5] += b.y; acc[6] += b.z; acc[7] += b.w;
    }
    uint32 H[8], M[8], L[8];
#pragma unroll
    for (int j = 0; j < 8; j++) split3(acc[j], H[j], M[j], L[j]);
    int T = n >> 4, m = n & 15, g = f >> 2, qq = f & 3;
    size_t cb = ((size_t)(T * 7 + g) * 3) * 512 + (size_t)(qq * 16 + m) * 8;
    *(uint4*)(AS + cb)        = make_uint4(H[0]|(H[1]<<16), H[2]|(H[3]<<16), H[4]|(H[5]<<16), H[6]|(H[7]<<16));
    *(uint4*)(AS + cb + 512)  = make_uint4(M[0]|(M[1]<<16), M[2]|(M[3]<<16), M[4]|(M[5]<<16), M[6]|(M[7]<<16));
    *(uint4*)(AS + cb + 1024) = make_uint4(L[0]|(L[1]<<16), L[2]|(L[3]<<16), L[4]|(L[5]<<16), L[6]|(L[7]<<16));
}

// ---------------------------------------------------------------- GRU (MFMA) v9
// 512-thread blocks (8 waves), 32 rows (rf=2), tiles ct = wave + 8t
// (wave0: 4 tiles, others 3) -> acc <= 32 AGPR, ~100 regs, 4 waves/SIMD.
// All k-loop loads (acts from AS, weights from WS) are coalesced 16B/lane
// chunk reads. Zero split VALU. One barrier before in-place h update.
__global__ __launch_bounds__(512, 4) void gru_mfma(
    ushort_t* __restrict__ AS, const ushort_t* __restrict__ WS,
    const float* __restrict__ bg) {
    const int tid = threadIdx.x;
    const int wave = tid >> 6;          // 0..7
    const int lane = tid & 63;
    const int m = lane & 15, q = lane >> 4;
    const int Tb0 = blockIdx.x * 2;

    f32x4 z = {0.f, 0.f, 0.f, 0.f};
    f32x4 acc[4][2];
#pragma unroll
    for (int t = 0; t < 4; t++) { acc[t][0] = z; acc[t][1] = z; }

    size_t wbase[4];
#pragma unroll
    for (int t = 0; t < 4; t++) {
        int ct = wave + 8 * t;
        wbase[t] = (ct < 25) ? ((size_t)ct * 10752 + (size_t)lane * 8) : 0;
    }
    const size_t ab0 = ((size_t)(Tb0 * 7) * 3) * 512 + (size_t)lane * 8;
    const size_t ab1 = ((size_t)((Tb0 + 1) * 7) * 3) * 512 + (size_t)lane * 8;

#define GPASS(Wreg, Fr)                                          \
    _Pragma("unroll")                                            \
    for (int t = 0; t < 4; t++) if (t < 3 || wave == 0) {        \
        acc[t][0] = mfma16(Wreg[t], Fr[0], acc[t][0]);           \
        acc[t][1] = mfma16(Wreg[t], Fr[1], acc[t][1]);           \
    }

    for (int kc = 0; kc < 7; kc++) {
        const size_t ka = (size_t)kc * 1536;    // 3 chunks per kc
        short8 f0[2], f1[2], f2[2];
        f0[0] = *(const short8*)(AS + ab0 + ka);
        f1[0] = *(const short8*)(AS + ab0 + ka + 512);
        f2[0] = *(const short8*)(AS + ab0 + ka + 1024);
        f0[1] = *(const short8*)(AS + ab1 + ka);
        f1[1] = *(const short8*)(AS + ab1 + ka + 512);
        f2[1] = *(const short8*)(AS + ab1 + ka + 1024);

        short8 w[4];
#pragma unroll
        for (int t = 0; t < 4; t++) if (t < 3 || wave == 0)
            w[t] = *(const short8*)(WS + wbase[t] + ka);
        GPASS(w, f0);                       // w0*f0
        GPASS(w, f1);                       // w0*f1
        GPASS(w, f2);                       // w0*f2
#pragma unroll
        for (int t = 0; t < 4; t++) if (t < 3 || wave == 0)
            w[t] = *(const short8*)(WS + wbase[t] + ka + 512);
        GPASS(w, f0);                       // w1*f0
        GPASS(w, f1);                       // w1*f1
#pragma unroll
        for (int t = 0; t < 4; t++) if (t < 3 || wave == 0)
            w[t] = *(const short8*)(WS + wbase[t] + ka + 1024);
        GPASS(w, f0);                       // w2*f0
    }
#undef GPASS

    __syncthreads();    // all AS reads complete before in-place h overwrite

    // epilogue: gates, h update, swizzled limb writes
#pragma unroll
    for (int t = 0; t < 4; t++) if (t < 3 || wave == 0) {
        const int ct = wave + 8 * t;        // < 25
        const int d = ct * 4 + q;           // < 100
        float4 b4 = *(const float4*)&bg[ct * 16 + 4 * q];
        const int fh = 14 + (d >> 3), j = d & 7;
        const int g = fh >> 2, qq = fh & 3;
#pragma unroll
        for (int rf = 0; rf < 2; rf++) {
            int T = Tb0 + rf;
            size_t cb = ((size_t)(T * 7 + g) * 3) * 512 + (size_t)(qq * 16 + m) * 8 + j;
            float hold = recon3(AS[cb], AS[cb + 512], AS[cb + 1024]);
            float rp = acc[t][rf][0] + b4.x;
            float zp = acc[t][rf][1] + b4.y;
            float np = acc[t][rf][2] + b4.z;
            float hh = acc[t][rf][3] + b4.w;
            float rr = 1.f / (1.f + __expf(-rp));
            float zz = 1.f / (1.f + __expf(-zp));
            float nw = tanhf(np + rr * hh);
            float hnew = (1.f - zz) * nw + zz * hold;
            uint32 h, mm, l; split3(hnew, h, mm, l);
            AS[cb] = (ushort_t)h; AS[cb + 512] = (ushort_t)mm;
            AS[cb + 1024] = (ushort_t)l;
        }
    }
}

// ---------------------------------------------------------------- classifier
__global__ __launch_bounds__(256) void classifier(
    const ushort_t* __restrict__ AS, const float* __restrict__ W1,
    const float* __restrict__ b1, const float* __restrict__ W2,
    const float* __restrict__ b2, float* __restrict__ out) {
    __shared__ float Wc[3000];
    __shared__ float bc[30];
    __shared__ float w2[30];
    int tid = threadIdx.x;
    for (int i = tid; i < 3000; i += 256) Wc[i] = W1[i];
    if (tid < 30) { bc[tid] = b1[tid]; w2[tid] = W2[tid]; }
    __syncthreads();
    int n = blockIdx.x * 256 + tid;
    int T = n >> 4, m = n & 15;
    float a[30];
#pragma unroll
    for (int j = 0; j < 30; j++) a[j] = bc[j];
    for (int f2 = 0; f2 < 13; f2++) {
        int f = 14 + f2, g = f >> 2, qq = f & 3;
        size_t cb = ((size_t)(T * 7 + g) * 3) * 512 + (size_t)(qq * 16 + m) * 8;
        int jmax = (f2 == 12) ? 4 : 8;
        for (int j = 0; j < jmax; j++) {
            float hv = recon3(AS[cb + j], AS[cb + 512 + j], AS[cb + 1024 + j]);
            int k = f2 * 8 + j;
#pragma unroll
            for (int jj = 0; jj < 30; jj++) a[jj] = fmaf(hv, Wc[k * 30 + jj], a[jj]);
        }
    }
    float s = b2[0];
#pragma unroll
    for (int j = 0; j < 30; j++) s = fmaf(fmaxf(a[j], 0.f), w2[j], s);
    out[n] = s;
}

// ---------------------------------------------------------------- launch
extern "C" void kernel_launch(void* const* d_in, const int* in_sizes, int n_in,
                              void* d_out, int out_size, void* d_ws, size_t ws_size,
                              hipStream_t stream) {
    const float* feat     = (const float*)d_in[0];
    const int*   er       = (const int*)d_in[1];
    const int*   ec       = (const int*)d_in[2];
    const float* init_W   = (const float*)d_in[3];
    const float* init_b   = (const float*)d_in[4];
    const float* fmsg_W1  = (const float*)d_in[5];
    const float* fmsg_b1  = (const float*)d_in[6];
    const float* fmsg_W2  = (const float*)d_in[7];
    const float* fmsg_b2  = (const float*)d_in[8];
    const float* bmsg_W1  = (const float*)d_in[9];
    const float* bmsg_b1  = (const float*)d_in[10];
    const float* bmsg_W2  = (const float*)d_in[11];
    const float* bmsg_b2  = (const float*)d_in[12];
    const float* fgru_Wih = (const float*)d_in[13];
    const float* fgru_Whh = (const float*)d_in[14];
    const float* fgru_bih = (const float*)d_in[15];
    const float* fgru_bhh = (const float*)d_in[16];
    const float* bgru_Wih = (const float*)d_in[17];
    const float* bgru_Whh = (const float*)d_in[18];
    const float* bgru_bih = (const float*)d_in[19];
    const float* bgru_bhh = (const float*)d_in[20];
    const float* cls_W1   = (const float*)d_in[21];
    const float* cls_b1   = (const float*)d_in[22];
    const float* cls_W2   = (const float*)d_in[23];
    const float* cls_b2   = (const float*)d_in[24];
    float* out = (float*)d_out;

    char* base = (char*)d_ws;
    size_t off = 0;
    auto alloc = [&](size_t bytes) -> void* {
        void* p = base + off;
        off += (bytes + 15) & ~(size_t)15;
        return p;
    };

    ushort_t* AS = (ushort_t*)alloc((size_t)NT * 21 * 1024);   // 168 MiB
    float*    fm = (float*)alloc((size_t)Nn * FM * 4);          // 54.5 MB

    ushort_t* fWS = (ushort_t*)alloc(25 * 7 * 3 * 512 * 2);     // 537.6 KB
    ushort_t* bWS = (ushort_t*)alloc(25 * 7 * 3 * 512 * 2);
    ushort_t* fA0 = (ushort_t*)alloc(8192 * 2);
    ushort_t* fA1 = (ushort_t*)alloc(8192 * 2);
    ushort_t* fA2 = (ushort_t*)alloc(8192 * 2);
    ushort_t* bA0 = (ushort_t*)alloc(8192 * 2);
    ushort_t* bA1 = (ushort_t*)alloc(8192 * 2);
    ushort_t* bA2 = (ushort_t*)alloc(8192 * 2);
    ushort_t* fB0 = (ushort_t*)alloc(7168 * 2);
    ushort_t* fB1 = (ushort_t*)alloc(7168 * 2);
    ushort_t* fB2 = (ushort_t*)alloc(7168 * 2);
    ushort_t* bB0 = (ushort_t*)alloc(7168 * 2);
    ushort_t* bB1 = (ushort_t*)alloc(7168 * 2);
    ushort_t* bB2 = (ushort_t*)alloc(7168 * 2);

    float* bgf  = (float*)alloc(400 * 4);
    float* bgb  = (float*)alloc(400 * 4);
    float* b1pf = (float*)alloc(64 * 4);
    float* b1pb = (float*)alloc(64 * 4);
    float* b2pf = (float*)alloc(112 * 4);
    float* b2pb = (float*)alloc(112 * 4);

    int* ptr_f = (int*)alloc((Nn + 1) * 4);
    int* ptr_b = (int*)alloc((Nn + 1) * 4);
    int* cnt   = (int*)alloc(2 * (size_t)Nn * 4);
    int* cnt_f = cnt;
    int* cnt_b = cnt + Nn;
    int* src_f = (int*)alloc((size_t)Ee * 4);
    int* src_b = (int*)alloc((size_t)Ee * 4);

    if (ws_size < off) {
        diag_kernel<<<(Nn + 255) / 256, 256, 0, stream>>>(out, (float)ws_size);
        return;
    }

    // CSR build
    zero_ints<<<(2 * Nn + 255) / 256, 256, 0, stream>>>(cnt, 2 * Nn);
    hist_kernel<<<Ee / 256, 256, 0, stream>>>(er, ec, cnt_f, cnt_b);
    scan_kernel<<<1, 1024, 0, stream>>>(cnt_f, ptr_f, Nn);
    scan_kernel<<<1, 1024, 0, stream>>>(cnt_b, ptr_b, Nn);
    fill_kernel<<<Ee / 256, 256, 0, stream>>>(er, ec, ptr_f, ptr_b, src_f, src_b);

    // weight prep
    prep_gru_w<<<(400 * 224 + 255) / 256, 256, 0, stream>>>(
        fgru_Wih, fgru_Whh, fgru_bih, fgru_bhh, fWS, bgf);
    prep_gru_w<<<(400 * 224 + 255) / 256, 256, 0, stream>>>(
        bgru_Wih, bgru_Whh, bgru_bih, bgru_bhh, bWS, bgb);
    prep_msg_w<<<(15360 + 255) / 256, 256, 0, stream>>>(
        fmsg_W1, fmsg_b1, fmsg_W2, fmsg_b2, fA0, fA1, fA2, b1pf, fB0, fB1, fB2, b2pf);
    prep_msg_w<<<(15360 + 255) / 256, 256, 0, stream>>>(
        bmsg_W1, bmsg_b1, bmsg_W2, bmsg_b2, bA0, bA1, bA2, b1pb, bB0, bB1, bB2, b2pb);

    // pads + h init
    zero_swz<<<NT, 64, 0, stream>>>(AS);
    init_h_kernel<<<13 * Nn / 256, 256, 0, stream>>>(feat, init_W, init_b, AS);

    const int gMsg  = Nn / 64;            // 2048
    const int gGru  = NT / 2;             // 4096 (32 rows per block)
    const int gGath = 13 * Nn / 256;      // 6656

    for (int rd = 0; rd < 20; rd++) {
        msg_mfma<<<gMsg, 256, 0, stream>>>(AS, fA0, fA1, fA2, b1pf,
                                           fB0, fB1, fB2, b2pf, fm);
        gather8<<<gGath, 256, 0, stream>>>(fm, ptr_f, src_f, AS);
        gru_mfma<<<gGru, 512, 0, stream>>>(AS, fWS, bgf);

        msg_mfma<<<gMsg, 256, 0, stream>>>(AS, bA0, bA1, bA2, b1pb,
                                           bB0, bB1, bB2, b2pb, fm);
        gather8<<<gGath, 256, 0, stream>>>(fm, ptr_b, src_b, AS);
        gru_mfma<<<gGru, 512, 0, stream>>>(AS, bWS, bgb);
    }

    classifier<<<Nn / 256, 256, 0, stream>>>(AS, cls_W1, cls_b1,
                                             cls_W2, cls_b2, out);
}